// Round 7
// baseline (635.016 us; speedup 1.0000x reference)
//
#include <hip/hip_runtime.h>
#include <hip/hip_cooperative_groups.h>

namespace cg = cooperative_groups;

typedef __attribute__((ext_vector_type(8))) short bf16x8;
typedef __attribute__((ext_vector_type(4))) float f32x4;

#define N_NODES 10000
#define N_EDGES 160000
#define FDIM    512
#define ELL     64
#define BM 64
#define BN 128
#define BK 64
#define TM 157              // ceil(10000/64)
#define NGEMM (TM * 4)      // 628
#define NSCAT 625           // 625*256 = 160000
#define NTRAN 768           // 3 * 256 tiles of 32x32
#define BLK 256

__device__ __forceinline__ float bf2f(unsigned int u) {
    union { unsigned int i; float f; } v; v.i = u << 16; return v.f;
}
__device__ __forceinline__ unsigned short f2bf(float f) {
    union { float f; unsigned int u; } v; v.f = f;
    unsigned int u = v.u;
    unsigned int r = u + 0x7fffu + ((u >> 16) & 1u);
    return (unsigned short)(r >> 16);
}
__device__ __forceinline__ void gload_lds16(const void* g, void* l) {
    __builtin_amdgcn_global_load_lds(
        (const __attribute__((address_space(1))) unsigned int*)g,
        (__attribute__((address_space(3))) unsigned int*)l, 16, 0, 0);
}
__device__ __forceinline__ int wave_is_f32(const unsigned int* w) {
    unsigned int v = w[(size_t)(threadIdx.x & 63) * 1000];
    unsigned int ex = (v >> 7) & 0xFFu;
    unsigned long long inb = __ballot(ex >= 100u && ex <= 140u);
    return (__popcll(inb) >= 48) ? 0 : 1;
}

// ---- GEMM tile: C[bm:bm+64][bn:bn+128] = A * W (Bt[n][k] = W[k][n]) ----------
__device__ __forceinline__ void gemm_tile(
        const void* Ap, const unsigned short* Bt, unsigned short* C,
        int M, int af32, int item, unsigned short* As, unsigned short* Bs,
        int tid, int lane, int wv) {
    const int K = FDIM;
    const int bm = (item % TM) * BM, bn = (item / TM) * BN;
    const int wm = (wv >> 1) * 32, wn = (wv & 1) * 64;
    const int lrow = lane & 15, lk = (lane >> 4) * 8;
    const unsigned short* Abf = (const unsigned short*)Ap;
    f32x4 acc[2][4] = {};

    for (int k0 = 0; k0 < K; k0 += BK) {
        if (!af32) {
            #pragma unroll
            for (int j = 0; j < 2; ++j) {                 // A: 64 rows
                int r0 = wv * 16 + j * 8;
                int arow = bm + r0 + (lane >> 3);
                if (arow >= M) arow = M - 1;              // clamp: discarded
                gload_lds16(Abf + (size_t)arow * K + k0 + (lane & 7) * 8,
                            &As[r0 * BK]);
            }
            #pragma unroll
            for (int j = 0; j < 4; ++j) {                 // B: 128 rows
                int r0 = wv * 32 + j * 8;
                gload_lds16(Bt + (size_t)(bn + r0 + (lane >> 3)) * K + k0 + (lane & 7) * 8,
                            &Bs[r0 * BK]);
            }
        } else {
            #pragma unroll
            for (int j = 0; j < 4; ++j) {
                int r0 = wv * 32 + j * 8;
                gload_lds16(Bt + (size_t)(bn + r0 + (lane >> 3)) * K + k0 + (lane & 7) * 8,
                            &Bs[r0 * BK]);
            }
            #pragma unroll
            for (int i = 0; i < 2; ++i) {                 // A f32 fallback
                int c = tid + i * 256;
                int row = c >> 3, seg = (c & 7) * 8;
                int grow = bm + row;
                bf16x8 va = {};
                if (grow < M) {
                    const float* Af = (const float*)Ap + (size_t)grow * K + k0 + seg;
                    f32x4 lo = *(const f32x4*)Af;
                    f32x4 hi = *(const f32x4*)(Af + 4);
                    #pragma unroll
                    for (int jj = 0; jj < 4; ++jj) {
                        va[jj]     = (short)f2bf(lo[jj]);
                        va[4 + jj] = (short)f2bf(hi[jj]);
                    }
                }
                *(bf16x8*)(&As[row * BK + seg]) = va;
            }
        }
        __syncthreads();
        #pragma unroll
        for (int half = 0; half < 2; ++half) {
            bf16x8 af[2], bfr[4];
            #pragma unroll
            for (int f = 0; f < 2; ++f)
                af[f] = *(const bf16x8*)(&As[(wm + f * 16 + lrow) * BK + half * 32 + lk]);
            #pragma unroll
            for (int f = 0; f < 4; ++f)
                bfr[f] = *(const bf16x8*)(&Bs[(wn + f * 16 + lrow) * BK + half * 32 + lk]);
            #pragma unroll
            for (int fm = 0; fm < 2; ++fm)
                #pragma unroll
                for (int fn = 0; fn < 4; ++fn)
                    acc[fm][fn] = __builtin_amdgcn_mfma_f32_16x16x32_bf16(
                        af[fm], bfr[fn], acc[fm][fn], 0, 0, 0);
        }
        __syncthreads();
    }

    int crow = (lane >> 4) * 4;
    int ccol = lane & 15;
    #pragma unroll
    for (int fm = 0; fm < 2; ++fm)
        #pragma unroll
        for (int fn = 0; fn < 4; ++fn)
            #pragma unroll
            for (int r = 0; r < 4; ++r) {
                int row = bm + wm + fm * 16 + crow + r;
                if (row < M)
                    C[(size_t)row * FDIM + bn + wn + fn * 16 + ccol] =
                        f2bf(acc[fm][fn][r]);
            }
}

// ---- agg phase: out[i] = sum norm*g[src] + g[i]/deg + b; 2 waves per node ----
__device__ __forceinline__ void agg_phase(
        const unsigned short* g, const void* bias, const int* cnt,
        const int* ell, void* out, int relu, int out_ext, int ff32,
        int gs, int lane, int wv) {
    for (int item = blockIdx.x; item < N_NODES / 2; item += gs) {
        int i = item * 2 + (wv >> 1);
        int f = (wv & 1) * 256 + lane * 4;
        int ci = cnt[i];
        int rows = (ci > ELL) ? ELL : ci;
        const int* ep = ell + (size_t)i * ELL;
        int   srcl = (lane < rows) ? ep[lane] : 0;
        int   cl   = (lane < rows) ? cnt[srcl] : 0;
        float wl   = rsqrtf((float)(cl + 1) * (float)(ci + 1));
        float a0 = 0.f, a1 = 0.f, a2 = 0.f, a3 = 0.f;
        int j = 0;
        for (; j + 8 <= rows; j += 8) {
            int s0 = __shfl(srcl, j);     float w0 = __shfl(wl, j);
            int s1 = __shfl(srcl, j + 1); float w1 = __shfl(wl, j + 1);
            int s2 = __shfl(srcl, j + 2); float w2 = __shfl(wl, j + 2);
            int s3 = __shfl(srcl, j + 3); float w3 = __shfl(wl, j + 3);
            int s4 = __shfl(srcl, j + 4); float w4 = __shfl(wl, j + 4);
            int s5 = __shfl(srcl, j + 5); float w5 = __shfl(wl, j + 5);
            int s6 = __shfl(srcl, j + 6); float w6 = __shfl(wl, j + 6);
            int s7 = __shfl(srcl, j + 7); float w7 = __shfl(wl, j + 7);
            uint2 v0 = *(const uint2*)(g + (size_t)s0 * FDIM + f);
            uint2 v1 = *(const uint2*)(g + (size_t)s1 * FDIM + f);
            uint2 v2 = *(const uint2*)(g + (size_t)s2 * FDIM + f);
            uint2 v3 = *(const uint2*)(g + (size_t)s3 * FDIM + f);
            uint2 v4 = *(const uint2*)(g + (size_t)s4 * FDIM + f);
            uint2 v5 = *(const uint2*)(g + (size_t)s5 * FDIM + f);
            uint2 v6 = *(const uint2*)(g + (size_t)s6 * FDIM + f);
            uint2 v7 = *(const uint2*)(g + (size_t)s7 * FDIM + f);
            a0 += w0 * bf2f(v0.x & 0xffffu); a1 += w0 * bf2f(v0.x >> 16);
            a2 += w0 * bf2f(v0.y & 0xffffu); a3 += w0 * bf2f(v0.y >> 16);
            a0 += w1 * bf2f(v1.x & 0xffffu); a1 += w1 * bf2f(v1.x >> 16);
            a2 += w1 * bf2f(v1.y & 0xffffu); a3 += w1 * bf2f(v1.y >> 16);
            a0 += w2 * bf2f(v2.x & 0xffffu); a1 += w2 * bf2f(v2.x >> 16);
            a2 += w2 * bf2f(v2.y & 0xffffu); a3 += w2 * bf2f(v2.y >> 16);
            a0 += w3 * bf2f(v3.x & 0xffffu); a1 += w3 * bf2f(v3.x >> 16);
            a2 += w3 * bf2f(v3.y & 0xffffu); a3 += w3 * bf2f(v3.y >> 16);
            a0 += w4 * bf2f(v4.x & 0xffffu); a1 += w4 * bf2f(v4.x >> 16);
            a2 += w4 * bf2f(v4.y & 0xffffu); a3 += w4 * bf2f(v4.y >> 16);
            a0 += w5 * bf2f(v5.x & 0xffffu); a1 += w5 * bf2f(v5.x >> 16);
            a2 += w5 * bf2f(v5.y & 0xffffu); a3 += w5 * bf2f(v5.y >> 16);
            a0 += w6 * bf2f(v6.x & 0xffffu); a1 += w6 * bf2f(v6.x >> 16);
            a2 += w6 * bf2f(v6.y & 0xffffu); a3 += w6 * bf2f(v6.y >> 16);
            a0 += w7 * bf2f(v7.x & 0xffffu); a1 += w7 * bf2f(v7.x >> 16);
            a2 += w7 * bf2f(v7.y & 0xffffu); a3 += w7 * bf2f(v7.y >> 16);
        }
        for (; j < rows; ++j) {
            int s = __shfl(srcl, j);
            float w = __shfl(wl, j);
            uint2 v = *(const uint2*)(g + (size_t)s * FDIM + f);
            a0 += w * bf2f(v.x & 0xffffu); a1 += w * bf2f(v.x >> 16);
            a2 += w * bf2f(v.y & 0xffffu); a3 += w * bf2f(v.y >> 16);
        }
        float wself = 1.0f / (float)(ci + 1);
        uint2 vs = *(const uint2*)(g + (size_t)i * FDIM + f);
        a0 += wself * bf2f(vs.x & 0xffffu); a1 += wself * bf2f(vs.x >> 16);
        a2 += wself * bf2f(vs.y & 0xffffu); a3 += wself * bf2f(vs.y >> 16);
        if (ff32) {
            f32x4 bb = *(const f32x4*)((const float*)bias + f);
            a0 += bb[0]; a1 += bb[1]; a2 += bb[2]; a3 += bb[3];
        } else {
            uint2 bb = *(const uint2*)((const unsigned short*)bias + f);
            a0 += bf2f(bb.x & 0xffffu); a1 += bf2f(bb.x >> 16);
            a2 += bf2f(bb.y & 0xffffu); a3 += bf2f(bb.y >> 16);
        }
        if (relu) {
            a0 = fmaxf(a0, 0.f); a1 = fmaxf(a1, 0.f);
            a2 = fmaxf(a2, 0.f); a3 = fmaxf(a3, 0.f);
        }
        if (out_ext && ff32) {
            f32x4 o = {a0, a1, a2, a3};
            *(f32x4*)((float*)out + (size_t)i * FDIM + f) = o;
        } else {
            uint2 o;
            o.x = (unsigned int)f2bf(a0) | ((unsigned int)f2bf(a1) << 16);
            o.y = (unsigned int)f2bf(a2) | ((unsigned int)f2bf(a3) << 16);
            *(uint2*)((unsigned short*)out + (size_t)i * FDIM + f) = o;
        }
    }
}

// ---- the mega kernel ----------------------------------------------------------
__global__ __launch_bounds__(256, 3) void mega_v7(
        const void* x, const void* ei,
        const void* W1, const void* b1, const void* W2, const void* b2,
        const void* W3, const void* b3, void* dout,
        int* flags, int* cnt, int* ell, unsigned short* Wt, unsigned short* g) {
    cg::grid_group gg = cg::this_grid();
    __shared__ __align__(16) char lds_raw[24576];
    unsigned short* As = (unsigned short*)lds_raw;            // 64*64
    unsigned short* Bs = (unsigned short*)lds_raw + BM * BK;  // 128*64
    const int b = blockIdx.x, tid = threadIdx.x;
    const int gs = gridDim.x;
    const int lane = tid & 63, wv = tid >> 6;
    unsigned short* h = (unsigned short*)dout;                // bf16 ping-pong

    // ---- P0: zero cnt; flags; transpose W1..3 ----
    for (int z = b * BLK + tid; z < N_NODES; z += gs * BLK) cnt[z] = 0;
    if (b == 0 && tid < 64) {
        const unsigned long long* e64 = (const unsigned long long*)ei;
        unsigned long long v = e64[(size_t)tid * 2500];
        unsigned long long big = __ballot(v > 0xFFFFFFFFull);
        const unsigned int* xw = (const unsigned int*)x;
        unsigned int w = xw[(size_t)tid * 1000];
        unsigned int ex = (w >> 7) & 0xFFu;
        unsigned long long inb = __ballot(ex >= 100u && ex <= 140u);
        if (tid == 0) {
            flags[0] = (big == 0ull) ? 1 : 0;              // int64?
            flags[1] = (__popcll(inb) >= 48) ? 0 : 1;      // f32?
        }
    }
    for (int item = b; item < NTRAN; item += gs) {
        unsigned short (*tile)[33] = (unsigned short (*)[33])lds_raw;
        int z = item >> 8, t = item & 255;
        const void* W = (z == 0) ? W1 : (z == 1) ? W2 : W3;
        unsigned short* outp = Wt + (size_t)z * FDIM * FDIM;
        int ff32w = wave_is_f32((const unsigned int*)W);
        int tx = tid & 31, ty = tid >> 5;                  // 32 x 8
        int xcol = (t & 15) * 32 + tx;
        int y0 = (t >> 4) * 32 + ty;
        #pragma unroll
        for (int j = 0; j < 32; j += 8) {
            int idx = (y0 + j) * FDIM + xcol;
            tile[ty + j][tx] = ff32w ? f2bf(((const float*)W)[idx])
                                     : ((const unsigned short*)W)[idx];
        }
        __syncthreads();
        int x2 = (t >> 4) * 32 + tx;
        int y2 = (t & 15) * 32 + ty;
        #pragma unroll
        for (int j = 0; j < 32; j += 8)
            outp[(y2 + j) * FDIM + x2] = tile[tx][ty + j];
        __syncthreads();
    }
    gg.sync();

    const int i64  = flags[0];
    const int ff32 = flags[1];

    // ---- G1 (gemm on x) + scatter (ELL build; cnt = slot counter = degree) ----
    for (int item = b; item < NGEMM + NSCAT; item += gs) {
        if (item < NGEMM) {
            gemm_tile(x, Wt, g, N_NODES, ff32, item, As, Bs, tid, lane, wv);
        } else {
            int e = (item - NGEMM) * 256 + tid;
            if (e < N_EDGES) {
                int r, c;
                if (i64) {
                    r = (int)((const long long*)ei)[e];
                    c = (int)((const long long*)ei)[N_EDGES + e];
                } else {
                    r = ((const int*)ei)[e];
                    c = ((const int*)ei)[N_EDGES + e];
                }
                int slot = atomicAdd(&cnt[c], 1);
                if (slot < ELL) ell[(size_t)c * ELL + slot] = r;
            }
        }
    }
    gg.sync();

    // ---- A1 ----
    agg_phase(g, b1, cnt, ell, h, 1, 0, ff32, gs, lane, wv);
    gg.sync();

    // ---- G2 ----
    for (int item = b; item < NGEMM; item += gs)
        gemm_tile(h, Wt + (size_t)FDIM * FDIM, g, N_NODES, 0, item, As, Bs,
                  tid, lane, wv);
    gg.sync();

    // ---- A2 ----
    agg_phase(g, b2, cnt, ell, h, 1, 0, ff32, gs, lane, wv);
    gg.sync();

    // ---- G3 ----
    for (int item = b; item < NGEMM; item += gs)
        gemm_tile(h, Wt + (size_t)2 * FDIM * FDIM, g, N_NODES, 0, item, As, Bs,
                  tid, lane, wv);
    gg.sync();

    // ---- A3 (final, f32 out iff floats are f32) ----
    agg_phase(g, b3, cnt, ell, dout, 0, 1, ff32, gs, lane, wv);
}

// ---------------- launcher ------------------------------------------------------
extern "C" void kernel_launch(void* const* d_in, const int* in_sizes, int n_in,
                              void* d_out, int out_size, void* d_ws, size_t ws_size,
                              hipStream_t stream) {
    (void)in_sizes; (void)n_in; (void)out_size; (void)ws_size;
    const void* x  = d_in[0];
    const void* ei = d_in[1];
    const void* W1 = d_in[2];
    const void* b1 = d_in[3];
    const void* W2 = d_in[4];
    const void* b2 = d_in[5];
    const void* W3 = d_in[6];
    const void* b3 = d_in[7];
    void* dout = d_out;

    char* p = (char*)d_ws;
    auto alloc = [&](size_t bytes) -> void* {
        void* r = (void*)p;
        p += (bytes + 255) & ~(size_t)255;
        return r;
    };
    int*  flags = (int*) alloc(16);
    int*  cnt   = (int*) alloc((size_t)N_NODES * 4);
    int*  ell   = (int*) alloc((size_t)N_NODES * ELL * 4);
    unsigned short* Wt = (unsigned short*)alloc((size_t)3 * FDIM * FDIM * 2);
    unsigned short* g  = (unsigned short*)alloc((size_t)N_NODES * FDIM * 2);
    // total ws use ~14.1 MB

    int nblk = 0;
    hipOccupancyMaxActiveBlocksPerMultiprocessor(&nblk, mega_v7, BLK, 0);
    if (nblk < 1) nblk = 1;
    unsigned int grid = (unsigned int)nblk * 256u;   // 256 CUs, all co-resident

    void* kargs[] = {&x, &ei, &W1, &b1, &W2, &b2, &W3, &b3, &dout,
                     &flags, &cnt, &ell, &Wt, &g};
    hipLaunchCooperativeKernel((const void*)mega_v7, dim3(grid), dim3(BLK),
                               kargs, 0, stream);
}

// Round 8
// 228.623 us; speedup vs baseline: 2.7776x; 2.7776x over previous
//
#include <hip/hip_runtime.h>

typedef __attribute__((ext_vector_type(8))) short bf16x8;
typedef __attribute__((ext_vector_type(4))) float f32x4;

#define N_NODES 10000
#define N_EDGES 160000
#define FDIM    512
#define ELL     64
// gemm1 tile
#define BM 64
#define BN 128
#define BK 64
#define TM 157              // ceil(10000/64)
#define NGEMM (TM * 4)      // 628
#define NSCAT 625           // 625*256 = 160000
#define NTRAN 768           // 3 * 256 tiles of 32x32
#define NZERO 40            // 40*256 >= 10000
// fused tile
#define FBM 48
#define FNB 209             // ceil(10000/48)
#define APAD 520            // A row stride in LDS (1040B = 65*16B, 2-way banks)

__device__ __forceinline__ float bf2f(unsigned int u) {
    union { unsigned int i; float f; } v; v.i = u << 16; return v.f;
}
__device__ __forceinline__ float bfs2f(short s) {
    return bf2f((unsigned int)(unsigned short)s);
}
__device__ __forceinline__ unsigned short f2bf(float f) {
    union { float f; unsigned int u; } v; v.f = f;
    unsigned int u = v.u;
    unsigned int r = u + 0x7fffu + ((u >> 16) & 1u);
    return (unsigned short)(r >> 16);
}
__device__ __forceinline__ void gload_lds16(const void* g, void* l) {
    __builtin_amdgcn_global_load_lds(
        (const __attribute__((address_space(1))) unsigned int*)g,
        (__attribute__((address_space(3))) unsigned int*)l, 16, 0, 0);
}
__device__ __forceinline__ int wave_is_f32(const unsigned int* w) {
    unsigned int v = w[(size_t)(threadIdx.x & 63) * 1000];
    unsigned int ex = (v >> 7) & 0xFFu;
    unsigned long long inb = __ballot(ex >= 100u && ex <= 140u);
    return (__popcll(inb) >= 48) ? 0 : 1;
}

// ---------------- N1: transpose W1..3 || zero cnt || flags ---------------------
__global__ __launch_bounds__(256) void prep_v8(
        const void* __restrict__ x, const void* __restrict__ ei,
        const void* __restrict__ W1, const void* __restrict__ W2,
        const void* __restrict__ W3, unsigned short* __restrict__ Wt,
        int* __restrict__ cnt, int* __restrict__ flags) {
    int b = blockIdx.x, tid = threadIdx.x;
    if (b < NTRAN) {
        __shared__ unsigned short tile[32][33];
        int z = b >> 8, t = b & 255;
        const void* W = (z == 0) ? W1 : (z == 1) ? W2 : W3;
        unsigned short* outp = Wt + (size_t)z * FDIM * FDIM;
        int ff32 = wave_is_f32((const unsigned int*)W);
        int tx = tid & 31, ty = tid >> 5;              // 32 x 8
        int xcol = (t & 15) * 32 + tx;
        int y0 = (t >> 4) * 32 + ty;
        #pragma unroll
        for (int j = 0; j < 32; j += 8) {
            int idx = (y0 + j) * FDIM + xcol;
            tile[ty + j][tx] = ff32 ? f2bf(((const float*)W)[idx])
                                    : ((const unsigned short*)W)[idx];
        }
        __syncthreads();
        int x2 = (t >> 4) * 32 + tx;
        int y2 = (t & 15) * 32 + ty;
        #pragma unroll
        for (int j = 0; j < 32; j += 8)
            outp[(y2 + j) * FDIM + x2] = tile[tx][ty + j];
    } else if (b < NTRAN + NZERO) {
        int i = (b - NTRAN) * 256 + tid;
        if (i < N_NODES) cnt[i] = 0;
    } else {
        if (tid < 64) {
            const unsigned long long* e64 = (const unsigned long long*)ei;
            unsigned long long v = e64[(size_t)tid * 2500];
            unsigned long long big = __ballot(v > 0xFFFFFFFFull);
            const unsigned int* xw = (const unsigned int*)x;
            unsigned int w = xw[(size_t)tid * 1000];
            unsigned int ex = (w >> 7) & 0xFFu;
            unsigned long long inb = __ballot(ex >= 100u && ex <= 140u);
            if (tid == 0) {
                flags[0] = (big == 0ull) ? 1 : 0;          // int64?
                flags[1] = (__popcll(inb) >= 48) ? 0 : 1;  // f32?
            }
        }
    }
}

// ---------------- N2: gemm1 (x*W1 -> g) + ELL scatter (slot=count) -------------
// LDS tiles XOR-swizzled: data for k-slot t of row n sits at LDS slot t^(n&7).
__global__ __launch_bounds__(256) void gemm_scat_v8(
        const void* __restrict__ Ap, const unsigned short* __restrict__ Bt,
        unsigned short* __restrict__ C, const int* __restrict__ flags,
        const void* __restrict__ ei, int* __restrict__ cnt,
        int* __restrict__ ell) {
    __shared__ unsigned short As[BM * BK];
    __shared__ unsigned short Bs[BN * BK];
    if (blockIdx.x >= NGEMM) {
        int e = (blockIdx.x - NGEMM) * 256 + threadIdx.x;
        if (e < N_EDGES) {
            int r, c;
            if (flags[0]) {
                r = (int)((const long long*)ei)[e];
                c = (int)((const long long*)ei)[N_EDGES + e];
            } else {
                r = ((const int*)ei)[e];
                c = ((const int*)ei)[N_EDGES + e];
            }
            int slot = atomicAdd(&cnt[c], 1);
            if (slot < ELL) ell[(size_t)c * ELL + slot] = r;
        }
        return;
    }
    const int K = FDIM;
    const int af32 = flags[1];
    const int tid = threadIdx.x;
    const int t = blockIdx.x;
    const int bm = (t % TM) * BM, bn = (t / TM) * BN;
    const int lane = tid & 63, wv = tid >> 6;
    const int wm = (wv >> 1) * 32, wn = (wv & 1) * 64;
    const int lrow = lane & 15;
    const int tsl = lane >> 4;               // 16B slot base (0..3)
    const int ksw = (lane & 7) ^ ((lane >> 3) & 7);   // swizzled stage k-slot
    const unsigned short* Abf = (const unsigned short*)Ap;
    f32x4 acc[2][4] = {};

    for (int k0 = 0; k0 < K; k0 += BK) {
        if (!af32) {
            #pragma unroll
            for (int j = 0; j < 2; ++j) {                 // A: 64 rows
                int r0 = wv * 16 + j * 8;
                int arow = bm + r0 + (lane >> 3);
                if (arow >= N_NODES) arow = N_NODES - 1;  // clamp: discarded
                gload_lds16(Abf + (size_t)arow * K + k0 + ksw * 8, &As[r0 * BK]);
            }
            #pragma unroll
            for (int j = 0; j < 4; ++j) {                 // B: 128 rows
                int r0 = wv * 32 + j * 8;
                gload_lds16(Bt + (size_t)(bn + r0 + (lane >> 3)) * K + k0 + ksw * 8,
                            &Bs[r0 * BK]);
            }
        } else {
            #pragma unroll
            for (int j = 0; j < 4; ++j) {
                int r0 = wv * 32 + j * 8;
                gload_lds16(Bt + (size_t)(bn + r0 + (lane >> 3)) * K + k0 + ksw * 8,
                            &Bs[r0 * BK]);
            }
            #pragma unroll
            for (int i = 0; i < 2; ++i) {                 // A f32 fallback
                int c = tid + i * 256;
                int row = c >> 3, sl = c & 7;
                int grow = bm + row;
                bf16x8 va = {};
                if (grow < N_NODES) {
                    const float* Af = (const float*)Ap + (size_t)grow * K + k0 + sl * 8;
                    f32x4 lo = *(const f32x4*)Af;
                    f32x4 hi = *(const f32x4*)(Af + 4);
                    #pragma unroll
                    for (int jj = 0; jj < 4; ++jj) {
                        va[jj]     = (short)f2bf(lo[jj]);
                        va[4 + jj] = (short)f2bf(hi[jj]);
                    }
                }
                *(bf16x8*)(&As[row * BK + ((sl ^ (row & 7)) * 8)]) = va;
            }
        }
        __syncthreads();
        #pragma unroll
        for (int half = 0; half < 2; ++half) {
            int ts = half * 4 + tsl;
            bf16x8 af[2], bfr[4];
            #pragma unroll
            for (int f = 0; f < 2; ++f) {
                int row = wm + f * 16 + lrow;
                af[f] = *(const bf16x8*)(&As[row * BK + ((ts ^ (lrow & 7)) * 8)]);
            }
            #pragma unroll
            for (int f = 0; f < 4; ++f) {
                int row = wn + f * 16 + lrow;
                bfr[f] = *(const bf16x8*)(&Bs[row * BK + ((ts ^ (lrow & 7)) * 8)]);
            }
            #pragma unroll
            for (int fm = 0; fm < 2; ++fm)
                #pragma unroll
                for (int fn = 0; fn < 4; ++fn)
                    acc[fm][fn] = __builtin_amdgcn_mfma_f32_16x16x32_bf16(
                        af[fm], bfr[fn], acc[fm][fn], 0, 0, 0);
        }
        __syncthreads();
    }

    int crow = (lane >> 4) * 4;
    int ccol = lane & 15;
    #pragma unroll
    for (int fm = 0; fm < 2; ++fm)
        #pragma unroll
        for (int fn = 0; fn < 4; ++fn)
            #pragma unroll
            for (int r = 0; r < 4; ++r) {
                int row = bm + wm + fm * 16 + crow + r;
                if (row < N_NODES)
                    C[(size_t)row * FDIM + bn + wn + fn * 16 + ccol] =
                        f2bf(acc[fm][fn][r]);
            }
}

// ---------------- N3/N4: fused agg(relu) -> LDS -> gemm ------------------------
// block: 48 rows, 6 waves. agg 48x512 into As (bf16), then C[48][512]=As*W.
__global__ __launch_bounds__(384) void fused_ag_v8(
        const unsigned short* __restrict__ gin, const void* __restrict__ bias,
        const int* __restrict__ cnt, const int* __restrict__ ell,
        const unsigned short* __restrict__ Bt, unsigned short* __restrict__ Cout,
        const int* __restrict__ flags) {
    __shared__ unsigned short As[FBM * APAD];   // ~50 KB
    __shared__ unsigned short Bs[512 * 64];     // 64 KB
    const int tid = threadIdx.x, lane = tid & 63, wv = tid / 64;   // wv 0..5
    const int bm = blockIdx.x * FBM;
    const int ff32 = flags[1];
    const int ksw = (lane & 7) ^ ((lane >> 3) & 7);

    // prefetch B k0=0 (completes under agg; barrier below waits it)
    for (int m = wv; m < 64; m += 6) {
        int r0 = m * 8;
        gload_lds16(Bt + (size_t)(r0 + (lane >> 3)) * FDIM + 0 + ksw * 8,
                    &Bs[r0 * 64]);
    }

    // ---- agg phase: wave wv -> rows [wv*8, wv*8+8), full 512-wide per row ----
    for (int rl = wv * 8; rl < wv * 8 + 8; ++rl) {
        int i = bm + rl;
        float a[8] = {};
        if (i < N_NODES) {
            int ci = cnt[i];
            int re = (ci > ELL) ? ELL : ci;
            const int* ep = ell + (size_t)i * ELL;
            int   srcl = (lane < re) ? ep[lane] : 0;
            int   cl   = (lane < re) ? cnt[srcl] : 0;
            float wl = rsqrtf((float)(cl + 1) * (float)(ci + 1));
            int j = 0;
            for (; j + 8 <= re; j += 8) {
                int s[8]; float w[8]; bf16x8 v[8];
                #pragma unroll
                for (int q = 0; q < 8; ++q) {
                    s[q] = __shfl(srcl, j + q); w[q] = __shfl(wl, j + q);
                }
                #pragma unroll
                for (int q = 0; q < 8; ++q)
                    v[q] = *(const bf16x8*)(gin + (size_t)s[q] * FDIM + lane * 8);
                #pragma unroll
                for (int q = 0; q < 8; ++q)
                    #pragma unroll
                    for (int tt = 0; tt < 8; ++tt) a[tt] += w[q] * bfs2f(v[q][tt]);
            }
            for (; j < re; ++j) {
                int s = __shfl(srcl, j); float w = __shfl(wl, j);
                bf16x8 v = *(const bf16x8*)(gin + (size_t)s * FDIM + lane * 8);
                #pragma unroll
                for (int tt = 0; tt < 8; ++tt) a[tt] += w * bfs2f(v[tt]);
            }
            float wself = 1.0f / (float)(ci + 1);
            bf16x8 vs = *(const bf16x8*)(gin + (size_t)i * FDIM + lane * 8);
            #pragma unroll
            for (int tt = 0; tt < 8; ++tt) a[tt] += wself * bfs2f(vs[tt]);
            if (ff32) {
                const float* B = (const float*)bias + lane * 8;
                #pragma unroll
                for (int tt = 0; tt < 8; ++tt) a[tt] += B[tt];
            } else {
                bf16x8 bb = *(const bf16x8*)((const unsigned short*)bias + lane * 8);
                #pragma unroll
                for (int tt = 0; tt < 8; ++tt) a[tt] += bfs2f(bb[tt]);
            }
            #pragma unroll
            for (int tt = 0; tt < 8; ++tt) a[tt] = fmaxf(a[tt], 0.f);  // relu
        }
        bf16x8 o;
        #pragma unroll
        for (int tt = 0; tt < 8; ++tt) o[tt] = (short)f2bf(a[tt]);
        *(bf16x8*)(&As[rl * APAD + lane * 8]) = o;
    }
    __syncthreads();    // As ready, Bs(k0=0) ready

    // ---- gemm phase: wave (wrow 0..2, wcol 0..1) = 16 rows x 256 cols --------
    const int wrow = wv % 3, wcol = wv / 3;
    const int lrow = lane & 15, tsl = lane >> 4;
    f32x4 acc[16] = {};
    for (int k0 = 0; k0 < FDIM; k0 += 64) {
        #pragma unroll
        for (int half = 0; half < 2; ++half) {
            bf16x8 af = *(const bf16x8*)(
                &As[(wrow * 16 + lrow) * APAD + k0 + half * 32 + tsl * 8]);
            int ts = half * 4 + tsl;
            #pragma unroll
            for (int ct = 0; ct < 16; ++ct) {
                int n = wcol * 256 + ct * 16 + lrow;
                bf16x8 bfr = *(const bf16x8*)(
                    &Bs[n * 64 + ((ts ^ (lrow & 7)) * 8)]);
                acc[ct] = __builtin_amdgcn_mfma_f32_16x16x32_bf16(
                    af, bfr, acc[ct], 0, 0, 0);
            }
        }
        __syncthreads();
        if (k0 + 64 < FDIM) {
            for (int m = wv; m < 64; m += 6) {
                int r0 = m * 8;
                gload_lds16(Bt + (size_t)(r0 + (lane >> 3)) * FDIM + (k0 + 64) + ksw * 8,
                            &Bs[r0 * 64]);
            }
        }
        __syncthreads();
    }
    int crow = (lane >> 4) * 4, ccol = lane & 15;
    #pragma unroll
    for (int ct = 0; ct < 16; ++ct)
        #pragma unroll
        for (int r = 0; r < 4; ++r) {
            int grow = bm + wrow * 16 + crow + r;
            if (grow < N_NODES)
                Cout[(size_t)grow * FDIM + wcol * 256 + ct * 16 + ccol] =
                    f2bf(acc[ct][r]);
        }
}

// ---------------- N5: final agg (no relu, f32 out iff f32 inputs) --------------
__global__ __launch_bounds__(256) void agg3_v8(
        const unsigned short* __restrict__ g, const void* __restrict__ bias,
        const int* __restrict__ cnt, const int* __restrict__ ell,
        void* __restrict__ out, const int* __restrict__ flags) {
    int wv = threadIdx.x >> 6, lane = threadIdx.x & 63;
    int i = blockIdx.x * 2 + (wv >> 1);
    int f = (wv & 1) * 256 + lane * 4;
    int ci = cnt[i];
    int re = (ci > ELL) ? ELL : ci;
    const int* ep = ell + (size_t)i * ELL;
    int   srcl = (lane < re) ? ep[lane] : 0;
    int   cl   = (lane < re) ? cnt[srcl] : 0;
    float wl = rsqrtf((float)(cl + 1) * (float)(ci + 1));
    float a0 = 0.f, a1 = 0.f, a2 = 0.f, a3 = 0.f;
    int j = 0;
    for (; j + 4 <= re; j += 4) {
        int s0 = __shfl(srcl, j);     float w0 = __shfl(wl, j);
        int s1 = __shfl(srcl, j + 1); float w1 = __shfl(wl, j + 1);
        int s2 = __shfl(srcl, j + 2); float w2 = __shfl(wl, j + 2);
        int s3 = __shfl(srcl, j + 3); float w3 = __shfl(wl, j + 3);
        uint2 v0 = *(const uint2*)(g + (size_t)s0 * FDIM + f);
        uint2 v1 = *(const uint2*)(g + (size_t)s1 * FDIM + f);
        uint2 v2 = *(const uint2*)(g + (size_t)s2 * FDIM + f);
        uint2 v3 = *(const uint2*)(g + (size_t)s3 * FDIM + f);
        a0 += w0 * bf2f(v0.x & 0xffffu); a1 += w0 * bf2f(v0.x >> 16);
        a2 += w0 * bf2f(v0.y & 0xffffu); a3 += w0 * bf2f(v0.y >> 16);
        a0 += w1 * bf2f(v1.x & 0xffffu); a1 += w1 * bf2f(v1.x >> 16);
        a2 += w1 * bf2f(v1.y & 0xffffu); a3 += w1 * bf2f(v1.y >> 16);
        a0 += w2 * bf2f(v2.x & 0xffffu); a1 += w2 * bf2f(v2.x >> 16);
        a2 += w2 * bf2f(v2.y & 0xffffu); a3 += w2 * bf2f(v2.y >> 16);
        a0 += w3 * bf2f(v3.x & 0xffffu); a1 += w3 * bf2f(v3.x >> 16);
        a2 += w3 * bf2f(v3.y & 0xffffu); a3 += w3 * bf2f(v3.y >> 16);
    }
    for (; j < re; ++j) {
        int s = __shfl(srcl, j); float w = __shfl(wl, j);
        uint2 v = *(const uint2*)(g + (size_t)s * FDIM + f);
        a0 += w * bf2f(v.x & 0xffffu); a1 += w * bf2f(v.x >> 16);
        a2 += w * bf2f(v.y & 0xffffu); a3 += w * bf2f(v.y >> 16);
    }
    float wself = 1.0f / (float)(ci + 1);
    uint2 vs = *(const uint2*)(g + (size_t)i * FDIM + f);
    a0 += wself * bf2f(vs.x & 0xffffu); a1 += wself * bf2f(vs.x >> 16);
    a2 += wself * bf2f(vs.y & 0xffffu); a3 += wself * bf2f(vs.y >> 16);
    int ff32 = flags[1];
    if (ff32) {
        f32x4 bb = *(const f32x4*)((const float*)bias + f);
        a0 += bb[0]; a1 += bb[1]; a2 += bb[2]; a3 += bb[3];
        f32x4 o = {a0, a1, a2, a3};
        *(f32x4*)((float*)out + (size_t)i * FDIM + f) = o;
    } else {
        uint2 bb = *(const uint2*)((const unsigned short*)bias + f);
        a0 += bf2f(bb.x & 0xffffu); a1 += bf2f(bb.x >> 16);
        a2 += bf2f(bb.y & 0xffffu); a3 += bf2f(bb.y >> 16);
        uint2 o;
        o.x = (unsigned int)f2bf(a0) | ((unsigned int)f2bf(a1) << 16);
        o.y = (unsigned int)f2bf(a2) | ((unsigned int)f2bf(a3) << 16);
        *(uint2*)((unsigned short*)out + (size_t)i * FDIM + f) = o;
    }
}

// ---------------- launcher ------------------------------------------------------
extern "C" void kernel_launch(void* const* d_in, const int* in_sizes, int n_in,
                              void* d_out, int out_size, void* d_ws, size_t ws_size,
                              hipStream_t stream) {
    (void)in_sizes; (void)n_in; (void)out_size; (void)ws_size;
    const void* x  = d_in[0];
    const void* ei = d_in[1];
    const void* W1 = d_in[2];
    const void* b1 = d_in[3];
    const void* W2 = d_in[4];
    const void* b2 = d_in[5];
    const void* W3 = d_in[6];
    const void* b3 = d_in[7];

    char* p = (char*)d_ws;
    auto alloc = [&](size_t bytes) -> void* {
        void* r = (void*)p;
        p += (bytes + 255) & ~(size_t)255;
        return r;
    };
    int*  flags = (int*) alloc(16);
    int*  cnt   = (int*) alloc((size_t)N_NODES * 4);
    int*  ell   = (int*) alloc((size_t)N_NODES * ELL * 4);
    unsigned short* Wt = (unsigned short*)alloc((size_t)3 * FDIM * FDIM * 2);
    unsigned short* g  = (unsigned short*)alloc((size_t)N_NODES * FDIM * 2);
    // ws use ~14.1 MB (same as proven v6/v7 footprint)

    unsigned short* Wt1 = Wt;
    unsigned short* Wt2 = Wt + (size_t)FDIM * FDIM;
    unsigned short* Wt3 = Wt + (size_t)2 * FDIM * FDIM;
    unsigned short* h   = (unsigned short*)d_out;       // bf16 scratch in d_out

    // N1: transpose + zero cnt + flags
    prep_v8<<<NTRAN + NZERO + 1, 256, 0, stream>>>(x, ei, W1, W2, W3, Wt, cnt, flags);
    // N2: g = x*W1  (+ ELL scatter builds cnt/ell)
    gemm_scat_v8<<<NGEMM + NSCAT, 256, 0, stream>>>(x, Wt1, g, flags, ei, cnt, ell);
    // N3: h(d_out) = agg(g,b1,relu) * W2
    fused_ag_v8<<<FNB, 384, 0, stream>>>(g, b1, cnt, ell, Wt2, h, flags);
    // N4: g = agg(h,b2,relu) * W3
    fused_ag_v8<<<FNB, 384, 0, stream>>>(h, b2, cnt, ell, Wt3, g, flags);
    // N5: out = agg(g,b3)
    agg3_v8<<<N_NODES / 2, 256, 0, stream>>>(g, b3, cnt, ell, d_out, flags);
}

// Round 9
// 207.733 us; speedup vs baseline: 3.0569x; 1.1006x over previous
//
#include <hip/hip_runtime.h>

typedef __attribute__((ext_vector_type(8))) short bf16x8;
typedef __attribute__((ext_vector_type(4))) float f32x4;

#define N_NODES 10000
#define N_EDGES 160000
#define FDIM    512
#define ELL     64
// gemm tile
#define BM 64
#define BN 128
#define BK 64
#define TM 157              // ceil(10000/64)
#define NGEMM (TM * 4)      // 628
#define NSCAT 625           // 625*256 = 160000
#define NTRAN 768           // 3 * 256 tiles of 32x32
#define NZERO 40            // 40*256 >= 10000
// agg slicing
#define SLICES 4
#define SLW 128             // feats per slice (2.5 MB slice -> L2-resident)
#define SLB 2500            // node-group blocks per slice (4 nodes/block)

__device__ __forceinline__ float bf2f(unsigned int u) {
    union { unsigned int i; float f; } v; v.i = u << 16; return v.f;
}
__device__ __forceinline__ unsigned short f2bf(float f) {
    union { float f; unsigned int u; } v; v.f = f;
    unsigned int u = v.u;
    unsigned int r = u + 0x7fffu + ((u >> 16) & 1u);
    return (unsigned short)(r >> 16);
}
__device__ __forceinline__ void gload_lds16(const void* g, void* l) {
    __builtin_amdgcn_global_load_lds(
        (const __attribute__((address_space(1))) unsigned int*)g,
        (__attribute__((address_space(3))) unsigned int*)l, 16, 0, 0);
}
__device__ __forceinline__ int wave_is_f32(const unsigned int* w) {
    unsigned int v = w[(size_t)(threadIdx.x & 63) * 1000];
    unsigned int ex = (v >> 7) & 0xFFu;
    unsigned long long inb = __ballot(ex >= 100u && ex <= 140u);
    return (__popcll(inb) >= 48) ? 0 : 1;
}

// ---------------- N1: transpose W1..3 || zero cnt || flags ---------------------
__global__ __launch_bounds__(256) void prep_v9(
        const void* __restrict__ x, const void* __restrict__ ei,
        const void* __restrict__ W1, const void* __restrict__ W2,
        const void* __restrict__ W3, unsigned short* __restrict__ Wt,
        int* __restrict__ cnt, int* __restrict__ flags) {
    int b = blockIdx.x, tid = threadIdx.x;
    if (b < NTRAN) {
        __shared__ unsigned short tile[32][33];
        int z = b >> 8, t = b & 255;
        const void* W = (z == 0) ? W1 : (z == 1) ? W2 : W3;
        unsigned short* outp = Wt + (size_t)z * FDIM * FDIM;
        int ff32 = wave_is_f32((const unsigned int*)W);
        int tx = tid & 31, ty = tid >> 5;              // 32 x 8
        int xcol = (t & 15) * 32 + tx;
        int y0 = (t >> 4) * 32 + ty;
        #pragma unroll
        for (int j = 0; j < 32; j += 8) {
            int idx = (y0 + j) * FDIM + xcol;
            tile[ty + j][tx] = ff32 ? f2bf(((const float*)W)[idx])
                                    : ((const unsigned short*)W)[idx];
        }
        __syncthreads();
        int x2 = (t >> 4) * 32 + tx;
        int y2 = (t & 15) * 32 + ty;
        #pragma unroll
        for (int j = 0; j < 32; j += 8)
            outp[(y2 + j) * FDIM + x2] = tile[tx][ty + j];
    } else if (b < NTRAN + NZERO) {
        int i = (b - NTRAN) * 256 + tid;
        if (i < N_NODES) cnt[i] = 0;
    } else {
        if (tid < 64) {
            const unsigned long long* e64 = (const unsigned long long*)ei;
            unsigned long long v = e64[(size_t)tid * 2500];
            unsigned long long big = __ballot(v > 0xFFFFFFFFull);
            const unsigned int* xw = (const unsigned int*)x;
            unsigned int w = xw[(size_t)tid * 1000];
            unsigned int ex = (w >> 7) & 0xFFu;
            unsigned long long inb = __ballot(ex >= 100u && ex <= 140u);
            if (tid == 0) {
                flags[0] = (big == 0ull) ? 1 : 0;          // int64?
                flags[1] = (__popcll(inb) >= 48) ? 0 : 1;  // f32?
            }
        }
    }
}

// ---------------- N2/N4/N6: swizzled MFMA GEMM (+opt ELL scatter tail) ---------
__global__ __launch_bounds__(256) void gemm_v9(
        const void* __restrict__ Ap, const unsigned short* __restrict__ Bt,
        unsigned short* __restrict__ C, int a_ext,
        const int* __restrict__ flags, const void* __restrict__ ei,
        int* __restrict__ cnt, int* __restrict__ ell) {
    __shared__ unsigned short As[BM * BK];
    __shared__ unsigned short Bs[BN * BK];
    if (blockIdx.x >= NGEMM) {
        int e = (blockIdx.x - NGEMM) * 256 + threadIdx.x;
        if (e < N_EDGES) {
            int r, c;
            if (flags[0]) {
                r = (int)((const long long*)ei)[e];
                c = (int)((const long long*)ei)[N_EDGES + e];
            } else {
                r = ((const int*)ei)[e];
                c = ((const int*)ei)[N_EDGES + e];
            }
            int slot = atomicAdd(&cnt[c], 1);
            if (slot < ELL) ell[(size_t)c * ELL + slot] = r;
        }
        return;
    }
    const int K = FDIM;
    const int af32 = a_ext ? flags[1] : 0;
    const int tid = threadIdx.x;
    const int t = blockIdx.x;
    const int bm = (t % TM) * BM, bn = (t / TM) * BN;
    const int lane = tid & 63, wv = tid >> 6;
    const int wm = (wv >> 1) * 32, wn = (wv & 1) * 64;
    const int lrow = lane & 15;
    const int tsl = lane >> 4;                        // 16B slot base (0..3)
    const int ksw = (lane & 7) ^ ((lane >> 3) & 7);   // swizzled stage k-slot
    const unsigned short* Abf = (const unsigned short*)Ap;
    f32x4 acc[2][4] = {};

    for (int k0 = 0; k0 < K; k0 += BK) {
        if (!af32) {
            #pragma unroll
            for (int j = 0; j < 2; ++j) {                 // A: 64 rows
                int r0 = wv * 16 + j * 8;
                int arow = bm + r0 + (lane >> 3);
                if (arow >= N_NODES) arow = N_NODES - 1;  // clamp: discarded
                gload_lds16(Abf + (size_t)arow * K + k0 + ksw * 8, &As[r0 * BK]);
            }
            #pragma unroll
            for (int j = 0; j < 4; ++j) {                 // B: 128 rows
                int r0 = wv * 32 + j * 8;
                gload_lds16(Bt + (size_t)(bn + r0 + (lane >> 3)) * K + k0 + ksw * 8,
                            &Bs[r0 * BK]);
            }
        } else {
            #pragma unroll
            for (int j = 0; j < 4; ++j) {
                int r0 = wv * 32 + j * 8;
                gload_lds16(Bt + (size_t)(bn + r0 + (lane >> 3)) * K + k0 + ksw * 8,
                            &Bs[r0 * BK]);
            }
            #pragma unroll
            for (int i = 0; i < 2; ++i) {                 // A f32 fallback
                int c = tid + i * 256;
                int row = c >> 3, sl = c & 7;
                int grow = bm + row;
                bf16x8 va = {};
                if (grow < N_NODES) {
                    const float* Af = (const float*)Ap + (size_t)grow * K + k0 + sl * 8;
                    f32x4 lo = *(const f32x4*)Af;
                    f32x4 hi = *(const f32x4*)(Af + 4);
                    #pragma unroll
                    for (int jj = 0; jj < 4; ++jj) {
                        va[jj]     = (short)f2bf(lo[jj]);
                        va[4 + jj] = (short)f2bf(hi[jj]);
                    }
                }
                *(bf16x8*)(&As[row * BK + ((sl ^ (row & 7)) * 8)]) = va;
            }
        }
        __syncthreads();
        #pragma unroll
        for (int half = 0; half < 2; ++half) {
            int ts = half * 4 + tsl;
            bf16x8 af[2], bfr[4];
            #pragma unroll
            for (int f = 0; f < 2; ++f) {
                int row = wm + f * 16 + lrow;
                af[f] = *(const bf16x8*)(&As[row * BK + ((ts ^ (lrow & 7)) * 8)]);
            }
            #pragma unroll
            for (int f = 0; f < 4; ++f) {
                int row = wn + f * 16 + lrow;
                bfr[f] = *(const bf16x8*)(&Bs[row * BK + ((ts ^ (lrow & 7)) * 8)]);
            }
            #pragma unroll
            for (int fm = 0; fm < 2; ++fm)
                #pragma unroll
                for (int fn = 0; fn < 4; ++fn)
                    acc[fm][fn] = __builtin_amdgcn_mfma_f32_16x16x32_bf16(
                        af[fm], bfr[fn], acc[fm][fn], 0, 0, 0);
        }
        __syncthreads();
    }

    int crow = (lane >> 4) * 4;
    int ccol = lane & 15;
    #pragma unroll
    for (int fm = 0; fm < 2; ++fm)
        #pragma unroll
        for (int fn = 0; fn < 4; ++fn)
            #pragma unroll
            for (int r = 0; r < 4; ++r) {
                int row = bm + wm + fm * 16 + crow + r;
                if (row < N_NODES)
                    C[(size_t)row * FDIM + bn + wn + fn * 16 + ccol] =
                        f2bf(acc[fm][fn][r]);
            }
}

// ---------------- N3/N5/N7: slice-blocked aggregation --------------------------
// Slice-major grid: blocks [s*SLB,(s+1)*SLB) process feat slice s (128 feats)
// for all 10000 nodes -> slice working set 2.5 MB stays L2-resident per XCD.
// Wave = 1 node; lane owns 2 feats (uint); per edge one 256B wave-read.
__global__ __launch_bounds__(256) void agg_sl_v9(
        const unsigned short* __restrict__ gin, const void* __restrict__ bias,
        const int* __restrict__ cnt, const int* __restrict__ ell,
        void* __restrict__ out, int relu, int out_ext,
        const int* __restrict__ flags) {
    const int wv = threadIdx.x >> 6, lane = threadIdx.x & 63;
    const int slice = blockIdx.x / SLB;
    const int i = (blockIdx.x % SLB) * 4 + wv;     // 2500*4 = 10000 exact
    const int fu = slice * (SLW / 2) + lane;       // uint index within row
    const unsigned int* g32 = (const unsigned int*)gin;   // row stride 256 uints
    int ci = cnt[i];
    int re = (ci > ELL) ? ELL : ci;
    const int* ep = ell + (size_t)i * ELL;
    int   srcl = (lane < re) ? ep[lane] : 0;
    int   cl   = (lane < re) ? cnt[srcl] : 0;
    float wl   = rsqrtf((float)(cl + 1) * (float)(ci + 1));
    float a0 = 0.f, a1 = 0.f;
    int j = 0;
    for (; j + 8 <= re; j += 8) {
        int s0 = __shfl(srcl, j);     float w0 = __shfl(wl, j);
        int s1 = __shfl(srcl, j + 1); float w1 = __shfl(wl, j + 1);
        int s2 = __shfl(srcl, j + 2); float w2 = __shfl(wl, j + 2);
        int s3 = __shfl(srcl, j + 3); float w3 = __shfl(wl, j + 3);
        int s4 = __shfl(srcl, j + 4); float w4 = __shfl(wl, j + 4);
        int s5 = __shfl(srcl, j + 5); float w5 = __shfl(wl, j + 5);
        int s6 = __shfl(srcl, j + 6); float w6 = __shfl(wl, j + 6);
        int s7 = __shfl(srcl, j + 7); float w7 = __shfl(wl, j + 7);
        unsigned int v0 = g32[(size_t)s0 * 256 + fu];
        unsigned int v1 = g32[(size_t)s1 * 256 + fu];
        unsigned int v2 = g32[(size_t)s2 * 256 + fu];
        unsigned int v3 = g32[(size_t)s3 * 256 + fu];
        unsigned int v4 = g32[(size_t)s4 * 256 + fu];
        unsigned int v5 = g32[(size_t)s5 * 256 + fu];
        unsigned int v6 = g32[(size_t)s6 * 256 + fu];
        unsigned int v7 = g32[(size_t)s7 * 256 + fu];
        a0 += w0 * bf2f(v0 & 0xffffu); a1 += w0 * bf2f(v0 >> 16);
        a0 += w1 * bf2f(v1 & 0xffffu); a1 += w1 * bf2f(v1 >> 16);
        a0 += w2 * bf2f(v2 & 0xffffu); a1 += w2 * bf2f(v2 >> 16);
        a0 += w3 * bf2f(v3 & 0xffffu); a1 += w3 * bf2f(v3 >> 16);
        a0 += w4 * bf2f(v4 & 0xffffu); a1 += w4 * bf2f(v4 >> 16);
        a0 += w5 * bf2f(v5 & 0xffffu); a1 += w5 * bf2f(v5 >> 16);
        a0 += w6 * bf2f(v6 & 0xffffu); a1 += w6 * bf2f(v6 >> 16);
        a0 += w7 * bf2f(v7 & 0xffffu); a1 += w7 * bf2f(v7 >> 16);
    }
    for (; j < re; ++j) {
        int s = __shfl(srcl, j); float w = __shfl(wl, j);
        unsigned int v = g32[(size_t)s * 256 + fu];
        a0 += w * bf2f(v & 0xffffu); a1 += w * bf2f(v >> 16);
    }
    float wself = 1.0f / (float)(ci + 1);
    unsigned int vs = g32[(size_t)i * 256 + fu];
    a0 += wself * bf2f(vs & 0xffffu); a1 += wself * bf2f(vs >> 16);
    int ff32 = flags[1];
    if (ff32) {
        const float* B = (const float*)bias + fu * 2;
        a0 += B[0]; a1 += B[1];
    } else {
        unsigned int bb = ((const unsigned int*)bias)[fu];
        a0 += bf2f(bb & 0xffffu); a1 += bf2f(bb >> 16);
    }
    if (relu) { a0 = fmaxf(a0, 0.f); a1 = fmaxf(a1, 0.f); }
    if (out_ext && ff32) {
        float2 o = {a0, a1};
        *(float2*)((float*)out + (size_t)i * FDIM + fu * 2) = o;
    } else {
        unsigned int o = (unsigned int)f2bf(a0) | ((unsigned int)f2bf(a1) << 16);
        ((unsigned int*)out)[(size_t)i * 256 + fu] = o;
    }
}

// ---------------- launcher ------------------------------------------------------
extern "C" void kernel_launch(void* const* d_in, const int* in_sizes, int n_in,
                              void* d_out, int out_size, void* d_ws, size_t ws_size,
                              hipStream_t stream) {
    (void)in_sizes; (void)n_in; (void)out_size; (void)ws_size;
    const void* x  = d_in[0];
    const void* ei = d_in[1];
    const void* W1 = d_in[2];
    const void* b1 = d_in[3];
    const void* W2 = d_in[4];
    const void* b2 = d_in[5];
    const void* W3 = d_in[6];
    const void* b3 = d_in[7];

    char* p = (char*)d_ws;
    auto alloc = [&](size_t bytes) -> void* {
        void* r = (void*)p;
        p += (bytes + 255) & ~(size_t)255;
        return r;
    };
    int*  flags = (int*) alloc(16);
    int*  cnt   = (int*) alloc((size_t)N_NODES * 4);
    int*  ell   = (int*) alloc((size_t)N_NODES * ELL * 4);
    unsigned short* Wt = (unsigned short*)alloc((size_t)3 * FDIM * FDIM * 2);
    unsigned short* g  = (unsigned short*)alloc((size_t)N_NODES * FDIM * 2);
    // ws use ~14.4 MB

    unsigned short* Wt1 = Wt;
    unsigned short* Wt2 = Wt + (size_t)FDIM * FDIM;
    unsigned short* Wt3 = Wt + (size_t)2 * FDIM * FDIM;
    unsigned short* h   = (unsigned short*)d_out;       // bf16 scratch in d_out

    // N1: transpose + zero cnt + flags
    prep_v9<<<NTRAN + NZERO + 1, 256, 0, stream>>>(x, ei, W1, W2, W3, Wt, cnt, flags);
    // N2: g = x*W1  (+ ELL scatter builds cnt/ell)
    gemm_v9<<<NGEMM + NSCAT, 256, 0, stream>>>(x, Wt1, g, 1, flags, ei, cnt, ell);
    // N3: h = relu(agg(g) + b1)
    agg_sl_v9<<<SLICES * SLB, 256, 0, stream>>>(g, b1, cnt, ell, h, 1, 0, flags);
    // N4: g = h*W2
    gemm_v9<<<NGEMM, 256, 0, stream>>>(h, Wt2, g, 0, flags, ei, cnt, ell);
    // N5: h = relu(agg(g) + b2)
    agg_sl_v9<<<SLICES * SLB, 256, 0, stream>>>(g, b2, cnt, ell, h, 1, 0, flags);
    // N6: g = h*W3
    gemm_v9<<<NGEMM, 256, 0, stream>>>(h, Wt3, g, 0, flags, ei, cnt, ell);
    // N7: out = agg(g) + b3   (f32 out iff f32 inputs)
    agg_sl_v9<<<SLICES * SLB, 256, 0, stream>>>(g, b3, cnt, ell, d_out, 0, 1, flags);
}